// Round 15
// baseline (37.487 us; speedup 1.0000x reference)
//
#include <hip/hip_runtime.h>
#include <hip/hip_fp16.h>
#include <math.h>

#define BB 16
#define CC 3
#define HH 512
#define WW 512
#define HW (HH * WW)
#define RAD 5
#define SEGV 32
#define NSEG (HH / SEGV)            // 16 segments per image
#define NSTRIP 5                    // 5 overlapping 128-col strips, 116 valid each
#define STRIPW 116
#define NTASK (BB * NSEG * NSTRIP)  // 1280 wave-tasks = 1280 single-wave blocks
#define NBLK NTASK                  // 5 blocks/CU exactly (even distribution)
#define NITER (SEGV + 2 * RAD)      // 42 row iterations (halo amp 1.31x)

// ---- DPP wave-shift helpers (VALU pipe, no DS) ----
#define DPP_WAVE_SHL1 0x130
#define DPP_WAVE_SHR1 0x138

template <int CTRL>
__device__ __forceinline__ float dpp_f(float x) {
    union { float f; int i; } u, o;
    u.f = x;
    o.i = __builtin_amdgcn_update_dpp(0, u.i, CTRL, 0xF, 0xF, true);
    return o.f;
}
template <int CTRL>
__device__ __forceinline__ __half2 dpp_h2(__half2 x) {
    union { __half2 h; int i; } u, o;
    u.h = x;
    o.i = __builtin_amdgcn_update_dpp(0, u.i, CTRL, 0xF, 0xF, true);
    return o.h;
}
#define SHL1F(x) dpp_f<DPP_WAVE_SHL1>(x)
#define SHR1F(x) dpp_f<DPP_WAVE_SHR1>(x)
#define SHL1H(x) dpp_h2<DPP_WAVE_SHL1>(x)
#define SHR1H(x) dpp_h2<DPP_WAVE_SHR1>(x)

// R14 champion body, SEGV 16 -> 32 (-19% total iters, -21% bytes),
// single-wave blocks (no LDS, no barriers anywhere).
__global__ __launch_bounds__(64) void fused_dpp(
    const float* __restrict__ pred, const float* __restrict__ target,
    float* __restrict__ ws_sq, float* __restrict__ ws_cos)
{
    const int lane = threadIdx.x;

    // bijective XCD-contiguous swizzle (1280 % 8 == 0): 160 blocks/XCD = 2 images
    const int bid = (int)blockIdx.x;
    const int swz = (bid & 7) * (NBLK / 8) + (bid >> 3);

    const int img   = swz / (NSEG * NSTRIP);
    const int rem   = swz % (NSEG * NSTRIP);
    const int seg   = rem / NSTRIP;
    const int strip = rem - seg * NSTRIP;

    const int y0   = seg * SEGV;
    const int col0 = strip * STRIPW - 6 + lane * 2;      // even
    const int colc = min(max(col0, 0), WW - 2);
    const float mx = (col0 >= 0 && col0 < WW) ? 1.f : 0.f;
    const bool vout = (lane >= 3) && (lane <= 60) && (col0 < WW);

    const long base = (long)img * (CC * HW);

    // prefetch row 0 (issue-early), depth-1 (VGPR-lean)
    float2 P0, P1, P2, T0, T1, T2;
    {
        const int y  = y0 - RAD;
        const int yc = y < 0 ? 0 : y;
        const long off = base + (long)yc * WW + colc;
        P0 = *(const float2*)(pred + off);
        P1 = *(const float2*)(pred + off + HW);
        P2 = *(const float2*)(pred + off + 2 * HW);
        T0 = *(const float2*)(target + off);
        T1 = *(const float2*)(target + off + HW);
        T2 = *(const float2*)(target + off + 2 * HW);
    }

    __half2 ring0[11], ring1[11], ringT[11];   // (hd0,hp0), (hd1,hp1), (ht0,ht1)
    float Sd0=0.f, Sd1=0.f, Sp0=0.f, Sp1=0.f, St0=0.f, St1=0.f;
    float sq = 0.f, cosacc = 0.f;

    #pragma unroll
    for (int it = 0; it < NITER; ++it) {
        const int y = y0 - RAD + it;
        const float msk = (y >= 0 && y < HH) ? mx : 0.f;

        const float2 p0=P0, p1=P1, p2=P2, t0=T0, t1=T1, t2=T2;
        if (it + 1 < NITER) {                     // prefetch next row
            const int y2  = y0 - RAD + it + 1;
            const int yc2 = min(max(y2, 0), HH - 1);
            const long off2 = base + (long)yc2 * WW + colc;
            P0 = *(const float2*)(pred + off2);
            P1 = *(const float2*)(pred + off2 + HW);
            P2 = *(const float2*)(pred + off2 + 2 * HW);
            T0 = *(const float2*)(target + off2);
            T1 = *(const float2*)(target + off2 + HW);
            T2 = *(const float2*)(target + off2 + 2 * HW);
        }

        // per-pixel dot/pp/tt, masked (zero padding outside image)
        const float ad = (p0.x*t0.x + p1.x*t1.x + p2.x*t2.x) * msk;
        const float bd = (p0.y*t0.y + p1.y*t1.y + p2.y*t2.y) * msk;
        const float ap = (p0.x*p0.x + p1.x*p1.x + p2.x*p2.x) * msk;
        const float bp = (p0.y*p0.y + p1.y*p1.y + p2.y*p2.y) * msk;
        const float at = (t0.x*t0.x + t1.x*t1.x + t2.x*t2.x) * msk;
        const float bt = (t0.y*t0.y + t1.y*t1.y + t2.y*t2.y) * msk;

        // PSNR squared error from maps: sum_c (p-t)^2 = pp - 2*dot + tt
        if (it >= RAD && it < RAD + SEGV && vout) {
            sq += (ap + at - 2.f * ad) + (bp + bt - 2.f * bd);
        }

        // ---- horizontal 11-window via DPP wave shifts (VALU only) ----
        __half2 h0dp, h1dp;
        {
            const __half2 Pk = __floats2half2_rn(ad + bd, ap + bp);
            const __half2 Ak = __floats2half2_rn(ad, ap);
            const __half2 Bk = __floats2half2_rn(bd, bp);
            __half2 w = Pk;
            w = __hadd2(Pk, SHR1H(w));
            w = __hadd2(Pk, SHR1H(w));
            w = __hadd2(Pk, SHR1H(w));
            w = __hadd2(Pk, SHR1H(w));            // sum pr_{i..i+4}
            const __half2 S5 = SHL1H(SHL1H(w));   // sum pr_{i-2..i+2}
            const __half2 eB = SHL1H(SHL1H(SHL1H(Bk)));
            const __half2 eA = SHR1H(SHR1H(SHR1H(Ak)));
            h0dp = __hadd2(eB, S5);
            h1dp = __hadd2(S5, eA);
        }
        __half2 hT;
        {
            const float pr = at + bt;
            float w = pr;
            w = pr + SHR1F(w);
            w = pr + SHR1F(w);
            w = pr + SHR1F(w);
            w = pr + SHR1F(w);
            const float S5 = SHL1F(SHL1F(w));
            const float eB = SHL1F(SHL1F(SHL1F(bt)));
            const float eA = SHR1F(SHR1F(SHR1F(at)));
            hT = __floats2half2_rn(eB + S5, S5 + eA);
        }

        // accumulate the QUANTIZED values -> ring subtract cancels exactly
        const float2 f0 = __half22float2(h0dp);
        const float2 f1 = __half22float2(h1dp);
        const float2 fT = __half22float2(hT);
        Sd0 += f0.x; Sp0 += f0.y;
        Sd1 += f1.x; Sp1 += f1.y;
        St0 += fT.x; St1 += fT.y;

        if (it >= 10) {
            if (vout) {
                cosacc += Sd0 * rsqrtf(fmaxf(Sp0 * St0, 1e-20f));
                cosacc += Sd1 * rsqrtf(fmaxf(Sp1 * St1, 1e-20f));
            }
            const float2 o0 = __half22float2(ring0[(it + 1) % 11]);
            const float2 o1 = __half22float2(ring1[(it + 1) % 11]);
            const float2 oT = __half22float2(ringT[(it + 1) % 11]);
            Sd0 -= o0.x; Sp0 -= o0.y;
            Sd1 -= o1.x; Sp1 -= o1.y;
            St0 -= oT.x; St1 -= oT.y;
        }
        ring0[it % 11] = h0dp;
        ring1[it % 11] = h1dp;
        ringT[it % 11] = hT;
    }

    // wave reduce -> per-block (= per-wave) partial stores
    #pragma unroll
    for (int o = 32; o > 0; o >>= 1) {
        cosacc += __shfl_down(cosacc, o);
        sq     += __shfl_down(sq, o);
    }
    if (lane == 0) {
        ws_cos[swz] = cosacc;
        ws_sq [swz] = sq;
    }
}

// ---------------- finalize: 1280 sq + 1280 cos partials ----------------
__global__ __launch_bounds__(256) void finalize4(
    const float* __restrict__ ws_sq, const float* __restrict__ ws_cos,
    float* __restrict__ out)
{
    __shared__ float sq_b[16];
    __shared__ float cred[4];
    const int tid = threadIdx.x;

    // sq: 80 partials per image; 16 threads/image, 5 values each
    const int b = tid >> 4, j = tid & 15;
    float s = 0.f;
    #pragma unroll
    for (int k = 0; k < 5; ++k) s += ws_sq[b * 80 + j * 5 + k];
    #pragma unroll
    for (int o = 8; o > 0; o >>= 1) s += __shfl_down(s, o, 16);
    if (j == 0) sq_b[b] = s;

    float c = 0.f;
    #pragma unroll
    for (int k = 0; k < 5; ++k) c += ws_cos[tid + 256 * k];
    #pragma unroll
    for (int o = 32; o > 0; o >>= 1) c += __shfl_down(c, o);
    if ((tid & 63) == 0) cred[tid >> 6] = c;
    __syncthreads();

    if (tid == 0) {
        const float csum = cred[0] + cred[1] + cred[2] + cred[3];
        const float scale = 4.342944819032518f;   // 10 / ln(10)
        float lsum = 0.f;
        for (int bb = 0; bb < 16; ++bb)
            lsum += logf(sq_b[bb] / (float)(CC * HW) + 1e-8f);
        out[0] = scale * (lsum / (float)BB) + (1.f - csum / (float)(BB * HW));
    }
}

extern "C" void kernel_launch(void* const* d_in, const int* in_sizes, int n_in,
                              void* d_out, int out_size, void* d_ws, size_t ws_size,
                              hipStream_t stream)
{
    const float* pred   = (const float*)d_in[0];
    const float* target = (const float*)d_in[1];

    float* ws_sq  = (float*)d_ws;                        // 1280 floats
    float* ws_cos = (float*)((char*)d_ws + 8192);        // 1280 floats

    fused_dpp<<<dim3(NBLK), 64, 0, stream>>>(pred, target, ws_sq, ws_cos);
    finalize4<<<1, 256, 0, stream>>>(ws_sq, ws_cos, (float*)d_out);
}

// Round 16
// 37.282 us; speedup vs baseline: 1.0055x; 1.0055x over previous
//
#include <hip/hip_runtime.h>
#include <hip/hip_fp16.h>
#include <math.h>

#define BB 16
#define CC 3
#define HH 512
#define WW 512
#define HW (HH * WW)
#define RAD 5
#define SEGV 32
#define NSEG (HH / SEGV)            // 16 segments per image
#define NSTRIP 5                    // 5 overlapping 128-col strips, 116 valid each
#define STRIPW 116
#define NTASK (BB * NSEG * NSTRIP)  // 1280 wave-tasks = 1280 single-wave blocks
#define NBLK NTASK                  // 5 blocks/CU exactly (even distribution)
#define NITER (SEGV + 2 * RAD)      // 42 row iterations (halo amp 1.31x)

// ---- DPP wave-shift helpers (VALU pipe, no DS) ----
#define DPP_WAVE_SHL1 0x130
#define DPP_WAVE_SHR1 0x138

template <int CTRL>
__device__ __forceinline__ float dpp_f(float x) {
    union { float f; int i; } u, o;
    u.f = x;
    o.i = __builtin_amdgcn_update_dpp(0, u.i, CTRL, 0xF, 0xF, true);
    return o.f;
}
template <int CTRL>
__device__ __forceinline__ __half2 dpp_h2(__half2 x) {
    union { __half2 h; int i; } u, o;
    u.h = x;
    o.i = __builtin_amdgcn_update_dpp(0, u.i, CTRL, 0xF, 0xF, true);
    return o.h;
}
#define SHL1F(x) dpp_f<DPP_WAVE_SHL1>(x)
#define SHR1F(x) dpp_f<DPP_WAVE_SHR1>(x)
#define SHL1H(x) dpp_h2<DPP_WAVE_SHL1>(x)
#define SHR1H(x) dpp_h2<DPP_WAVE_SHR1>(x)

// R14 champion body, SEGV 16 -> 32 (-19% total iters, -21% bytes),
// single-wave blocks (no LDS, no barriers anywhere).
__global__ __launch_bounds__(64) void fused_dpp(
    const float* __restrict__ pred, const float* __restrict__ target,
    float* __restrict__ ws_sq, float* __restrict__ ws_cos)
{
    const int lane = threadIdx.x;

    // bijective XCD-contiguous swizzle (1280 % 8 == 0): 160 blocks/XCD = 2 images
    const int bid = (int)blockIdx.x;
    const int swz = (bid & 7) * (NBLK / 8) + (bid >> 3);

    const int img   = swz / (NSEG * NSTRIP);
    const int rem   = swz % (NSEG * NSTRIP);
    const int seg   = rem / NSTRIP;
    const int strip = rem - seg * NSTRIP;

    const int y0   = seg * SEGV;
    const int col0 = strip * STRIPW - 6 + lane * 2;      // even
    const int colc = min(max(col0, 0), WW - 2);
    const float mx = (col0 >= 0 && col0 < WW) ? 1.f : 0.f;
    const bool vout = (lane >= 3) && (lane <= 60) && (col0 < WW);

    const long base = (long)img * (CC * HW);

    // prefetch row 0 (issue-early), depth-1 (VGPR-lean)
    float2 P0, P1, P2, T0, T1, T2;
    {
        const int y  = y0 - RAD;
        const int yc = y < 0 ? 0 : y;
        const long off = base + (long)yc * WW + colc;
        P0 = *(const float2*)(pred + off);
        P1 = *(const float2*)(pred + off + HW);
        P2 = *(const float2*)(pred + off + 2 * HW);
        T0 = *(const float2*)(target + off);
        T1 = *(const float2*)(target + off + HW);
        T2 = *(const float2*)(target + off + 2 * HW);
    }

    __half2 ring0[11], ring1[11], ringT[11];   // (hd0,hp0), (hd1,hp1), (ht0,ht1)
    float Sd0=0.f, Sd1=0.f, Sp0=0.f, Sp1=0.f, St0=0.f, St1=0.f;
    float sq = 0.f, cosacc = 0.f;

    #pragma unroll
    for (int it = 0; it < NITER; ++it) {
        const int y = y0 - RAD + it;
        const float msk = (y >= 0 && y < HH) ? mx : 0.f;

        const float2 p0=P0, p1=P1, p2=P2, t0=T0, t1=T1, t2=T2;
        if (it + 1 < NITER) {                     // prefetch next row
            const int y2  = y0 - RAD + it + 1;
            const int yc2 = min(max(y2, 0), HH - 1);
            const long off2 = base + (long)yc2 * WW + colc;
            P0 = *(const float2*)(pred + off2);
            P1 = *(const float2*)(pred + off2 + HW);
            P2 = *(const float2*)(pred + off2 + 2 * HW);
            T0 = *(const float2*)(target + off2);
            T1 = *(const float2*)(target + off2 + HW);
            T2 = *(const float2*)(target + off2 + 2 * HW);
        }

        // per-pixel dot/pp/tt, masked (zero padding outside image)
        const float ad = (p0.x*t0.x + p1.x*t1.x + p2.x*t2.x) * msk;
        const float bd = (p0.y*t0.y + p1.y*t1.y + p2.y*t2.y) * msk;
        const float ap = (p0.x*p0.x + p1.x*p1.x + p2.x*p2.x) * msk;
        const float bp = (p0.y*p0.y + p1.y*p1.y + p2.y*p2.y) * msk;
        const float at = (t0.x*t0.x + t1.x*t1.x + t2.x*t2.x) * msk;
        const float bt = (t0.y*t0.y + t1.y*t1.y + t2.y*t2.y) * msk;

        // PSNR squared error from maps: sum_c (p-t)^2 = pp - 2*dot + tt
        if (it >= RAD && it < RAD + SEGV && vout) {
            sq += (ap + at - 2.f * ad) + (bp + bt - 2.f * bd);
        }

        // ---- horizontal 11-window via DPP wave shifts (VALU only) ----
        __half2 h0dp, h1dp;
        {
            const __half2 Pk = __floats2half2_rn(ad + bd, ap + bp);
            const __half2 Ak = __floats2half2_rn(ad, ap);
            const __half2 Bk = __floats2half2_rn(bd, bp);
            __half2 w = Pk;
            w = __hadd2(Pk, SHR1H(w));
            w = __hadd2(Pk, SHR1H(w));
            w = __hadd2(Pk, SHR1H(w));
            w = __hadd2(Pk, SHR1H(w));            // sum pr_{i..i+4}
            const __half2 S5 = SHL1H(SHL1H(w));   // sum pr_{i-2..i+2}
            const __half2 eB = SHL1H(SHL1H(SHL1H(Bk)));
            const __half2 eA = SHR1H(SHR1H(SHR1H(Ak)));
            h0dp = __hadd2(eB, S5);
            h1dp = __hadd2(S5, eA);
        }
        __half2 hT;
        {
            const float pr = at + bt;
            float w = pr;
            w = pr + SHR1F(w);
            w = pr + SHR1F(w);
            w = pr + SHR1F(w);
            w = pr + SHR1F(w);
            const float S5 = SHL1F(SHL1F(w));
            const float eB = SHL1F(SHL1F(SHL1F(bt)));
            const float eA = SHR1F(SHR1F(SHR1F(at)));
            hT = __floats2half2_rn(eB + S5, S5 + eA);
        }

        // accumulate the QUANTIZED values -> ring subtract cancels exactly
        const float2 f0 = __half22float2(h0dp);
        const float2 f1 = __half22float2(h1dp);
        const float2 fT = __half22float2(hT);
        Sd0 += f0.x; Sp0 += f0.y;
        Sd1 += f1.x; Sp1 += f1.y;
        St0 += fT.x; St1 += fT.y;

        if (it >= 10) {
            if (vout) {
                cosacc += Sd0 * rsqrtf(fmaxf(Sp0 * St0, 1e-20f));
                cosacc += Sd1 * rsqrtf(fmaxf(Sp1 * St1, 1e-20f));
            }
            const float2 o0 = __half22float2(ring0[(it + 1) % 11]);
            const float2 o1 = __half22float2(ring1[(it + 1) % 11]);
            const float2 oT = __half22float2(ringT[(it + 1) % 11]);
            Sd0 -= o0.x; Sp0 -= o0.y;
            Sd1 -= o1.x; Sp1 -= o1.y;
            St0 -= oT.x; St1 -= oT.y;
        }
        ring0[it % 11] = h0dp;
        ring1[it % 11] = h1dp;
        ringT[it % 11] = hT;
    }

    // wave reduce -> per-block (= per-wave) partial stores
    #pragma unroll
    for (int o = 32; o > 0; o >>= 1) {
        cosacc += __shfl_down(cosacc, o);
        sq     += __shfl_down(sq, o);
    }
    if (lane == 0) {
        ws_cos[swz] = cosacc;
        ws_sq [swz] = sq;
    }
}

// ---------------- finalize: 1280 sq + 1280 cos partials ----------------
__global__ __launch_bounds__(256) void finalize4(
    const float* __restrict__ ws_sq, const float* __restrict__ ws_cos,
    float* __restrict__ out)
{
    __shared__ float sq_b[16];
    __shared__ float cred[4];
    const int tid = threadIdx.x;

    // sq: 80 partials per image; 16 threads/image, 5 values each
    const int b = tid >> 4, j = tid & 15;
    float s = 0.f;
    #pragma unroll
    for (int k = 0; k < 5; ++k) s += ws_sq[b * 80 + j * 5 + k];
    #pragma unroll
    for (int o = 8; o > 0; o >>= 1) s += __shfl_down(s, o, 16);
    if (j == 0) sq_b[b] = s;

    float c = 0.f;
    #pragma unroll
    for (int k = 0; k < 5; ++k) c += ws_cos[tid + 256 * k];
    #pragma unroll
    for (int o = 32; o > 0; o >>= 1) c += __shfl_down(c, o);
    if ((tid & 63) == 0) cred[tid >> 6] = c;
    __syncthreads();

    if (tid == 0) {
        const float csum = cred[0] + cred[1] + cred[2] + cred[3];
        const float scale = 4.342944819032518f;   // 10 / ln(10)
        float lsum = 0.f;
        for (int bb = 0; bb < 16; ++bb)
            lsum += logf(sq_b[bb] / (float)(CC * HW) + 1e-8f);
        out[0] = scale * (lsum / (float)BB) + (1.f - csum / (float)(BB * HW));
    }
}

extern "C" void kernel_launch(void* const* d_in, const int* in_sizes, int n_in,
                              void* d_out, int out_size, void* d_ws, size_t ws_size,
                              hipStream_t stream)
{
    const float* pred   = (const float*)d_in[0];
    const float* target = (const float*)d_in[1];

    float* ws_sq  = (float*)d_ws;                        // 1280 floats
    float* ws_cos = (float*)((char*)d_ws + 8192);        // 1280 floats

    fused_dpp<<<dim3(NBLK), 64, 0, stream>>>(pred, target, ws_sq, ws_cos);
    finalize4<<<1, 256, 0, stream>>>(ws_sq, ws_cos, (float*)d_out);
}